// Round 6
// baseline (371.581 us; speedup 1.0000x reference)
//
#include <hip/hip_runtime.h>
#include <hip/hip_bf16.h>

// Attention round 9: 4-blocks/CU attn + launch fusion.
//  - attn: round-5 structure (128-q blocks, 4 waves x 32 q, balanced per-CU
//    qtile map, 2-buffer depth-1 prefetch) with Pw shrunk to a per-sub-reused
//    [4][16][64] XOR-swizzled buffer -> LDS exactly 40960 B -> 4 resident
//    blocks/CU and the 1024-block grid is fully resident (no dispatch tail).
//  - fused_pre = conv_x + pack_em in one launch; conv_w3 = Wq/Wk/Wv transposes
//    in one launch (gridDim.z) -> 10 -> 7 dispatches.
//  - EM loads before STAGE; cvt_pk packing; setprio; exp2 softmax; XCD-grouped
//    head placement; XCD-local qkv/out swizzles.
// B=4 S=2048 D=1024 H=16 d=64.
// ws (bf16): Q(prescaled) | K | V | {Xbf -> Aout}; WoT overwrites Q slot after attn.
// d_out temp: WcatT @ +512KB (6MB) | V^T @ +8MB (16MB) | EM @ +24MB (8MB).

using bf16 = __hip_bfloat16;
typedef __attribute__((ext_vector_type(8))) short short8;
typedef __attribute__((ext_vector_type(4))) float floatx4;

#define kB 4
#define kS 2048
#define kDM 1024
#define kH 16
#define kDH 64
#define kHeadElems ((size_t)kB * kH * kS * kDH)   /* 8388608 */
#define STR 72

#if __has_builtin(__builtin_amdgcn_exp2f)
#define EXP2(x) __builtin_amdgcn_exp2f(x)
#else
#define EXP2(x) __expf((x) * 0.69314718056f)
#endif

__device__ __forceinline__ unsigned short f2bf(float f) {
    union { float f; unsigned u; } x{f};
    unsigned r = x.u + 0x7fff + ((x.u >> 16) & 1);
    return (unsigned short)(r >> 16);
}
__device__ __forceinline__ unsigned cvt_pk_bf16(float lo, float hi) {
    unsigned r;
    asm("v_cvt_pk_bf16_f32 %0, %1, %2" : "=v"(r) : "v"(lo), "v"(hi));
    return r;
}
__device__ __forceinline__ void gl_lds16(const void* g, void* l) {
    __builtin_amdgcn_global_load_lds(
        (const __attribute__((address_space(1))) unsigned int*)g,
        (__attribute__((address_space(3))) unsigned int*)l, 16, 0, 0);
}

// ---------------------------------------------------------------------------
// fused_pre: blocks [0,4096) = conv_x (fp32 -> bf16, 8/thread);
//            blocks [4096,6144) = pack_em (expanded post-softmax AND-mask).
// ---------------------------------------------------------------------------
__global__ __launch_bounds__(256)
void fused_pre(const float* __restrict__ X, bf16* __restrict__ Xb,
               const int* __restrict__ mask_aft, unsigned short* __restrict__ EM)
{
    const int bid = blockIdx.x;
    if (bid < 4096) {
        const size_t i = ((size_t)bid * 256 + threadIdx.x) * 8;
        const float4 a = *(const float4*)(X + i);
        const float4 b = *(const float4*)(X + i + 4);
        union { unsigned short u[8]; uint4 v; } o;
        o.u[0] = f2bf(a.x); o.u[1] = f2bf(a.y); o.u[2] = f2bf(a.z); o.u[3] = f2bf(a.w);
        o.u[4] = f2bf(b.x); o.u[5] = f2bf(b.y); o.u[6] = f2bf(b.z); o.u[7] = f2bf(b.w);
        *(uint4*)(Xb + i) = o.v;
    } else {
        const size_t i = ((size_t)(bid - 4096) * 256 + threadIdx.x) * 8;
        const int q  = (int)(i >> 11);
        const int k0 = (int)(i & 2047);
        const int4 m0 = *(const int4*)(mask_aft + i);
        const int4 m1 = *(const int4*)(mask_aft + i + 4);
        union { unsigned short u[8]; uint4 v; } o;
        o.u[0] = (m0.x || (k0 + 0) > q) ? 0 : 0xFFFFu;
        o.u[1] = (m0.y || (k0 + 1) > q) ? 0 : 0xFFFFu;
        o.u[2] = (m0.z || (k0 + 2) > q) ? 0 : 0xFFFFu;
        o.u[3] = (m0.w || (k0 + 3) > q) ? 0 : 0xFFFFu;
        o.u[4] = (m1.x || (k0 + 4) > q) ? 0 : 0xFFFFu;
        o.u[5] = (m1.y || (k0 + 5) > q) ? 0 : 0xFFFFu;
        o.u[6] = (m1.z || (k0 + 6) > q) ? 0 : 0xFFFFu;
        o.u[7] = (m1.w || (k0 + 7) > q) ? 0 : 0xFFFFu;
        *(uint4*)(EM + i) = o.v;
    }
}

// ---------------------------------------------------------------------------
// conv_w3: W [1024][1024] fp32 -> W^T bf16, z selects Wq/Wk/Wv.
// ---------------------------------------------------------------------------
__global__ __launch_bounds__(256)
void conv_w3(const float* __restrict__ Wq, const float* __restrict__ Wk,
             const float* __restrict__ Wv, bf16* __restrict__ WT)
{
    const float* W = (blockIdx.z == 0) ? Wq : (blockIdx.z == 1) ? Wk : Wv;
    bf16* dst = WT + (size_t)blockIdx.z * kDM * kDM;
    __shared__ unsigned short Ls[64][STR];
    const int k0 = blockIdx.x * 64, n0 = blockIdx.y * 64;
    const int tid = threadIdx.x;
    const int r16 = tid >> 4, c4 = (tid & 15) * 4;
    #pragma unroll
    for (int it = 0; it < 4; ++it) {
        const int r = it * 16 + r16;
        const float4 v = *(const float4*)(W + (size_t)(k0 + r) * kDM + n0 + c4);
        Ls[c4 + 0][r] = f2bf(v.x); Ls[c4 + 1][r] = f2bf(v.y);
        Ls[c4 + 2][r] = f2bf(v.z); Ls[c4 + 3][r] = f2bf(v.w);
    }
    __syncthreads();
    #pragma unroll
    for (int it = 0; it < 4; ++it) {
        const int rn = it * 16 + r16;
        ushort4 u;
        u.x = Ls[rn][c4 + 0]; u.y = Ls[rn][c4 + 1];
        u.z = Ls[rn][c4 + 2]; u.w = Ls[rn][c4 + 3];
        *(ushort4*)(dst + (size_t)(n0 + rn) * kDM + k0 + c4) = u;
    }
}

// ---------------------------------------------------------------------------
// conv_wT: single W transpose (Wo, after attn frees the Q slot).
// ---------------------------------------------------------------------------
__global__ __launch_bounds__(256)
void conv_wT(const float* __restrict__ W, bf16* __restrict__ WT)
{
    __shared__ unsigned short Ls[64][STR];
    const int k0 = blockIdx.x * 64, n0 = blockIdx.y * 64;
    const int tid = threadIdx.x;
    const int r16 = tid >> 4, c4 = (tid & 15) * 4;
    #pragma unroll
    for (int it = 0; it < 4; ++it) {
        const int r = it * 16 + r16;
        const float4 v = *(const float4*)(W + (size_t)(k0 + r) * kDM + n0 + c4);
        Ls[c4 + 0][r] = f2bf(v.x); Ls[c4 + 1][r] = f2bf(v.y);
        Ls[c4 + 2][r] = f2bf(v.z); Ls[c4 + 3][r] = f2bf(v.w);
    }
    __syncthreads();
    #pragma unroll
    for (int it = 0; it < 4; ++it) {
        const int rn = it * 16 + r16;
        ushort4 u;
        u.x = Ls[rn][c4 + 0]; u.y = Ls[rn][c4 + 1];
        u.z = Ls[rn][c4 + 2]; u.w = Ls[rn][c4 + 3];
        *(ushort4*)(WT + (size_t)(n0 + rn) * kDM + k0 + c4) = u;
    }
}

// ---------------------------------------------------------------------------
// qkv_mfma: A[8192][1024] @ WcatT[3072][1024]^T; scatter into Q/K/V [B,H,S,64].
// Q pre-scaled by 0.125*log2(e). XCD-local swizzle.
// ---------------------------------------------------------------------------
__global__ __launch_bounds__(256)
void qkv_mfma(const bf16* __restrict__ A, const bf16* __restrict__ BT,
              bf16* __restrict__ ws)
{
    __shared__ __align__(16) unsigned short At[128][32];
    __shared__ __align__(16) unsigned short Bt[128][32];
    const int tid = threadIdx.x;
    const int w = tid >> 6, lane = tid & 63;
    const int quad = (tid >> 4) & 3, col = tid & 15;
    const int wm = w >> 1, wn = w & 1;
    const int flat = blockIdx.x + blockIdx.y * 24;
    const int xcd = flat & 7;
    const int i2 = flat >> 3;                  // [0,192)
    const int n0 = (xcd * 3 + (i2 % 3)) * 128;
    const int m0 = (i2 / 3) * 128;

    const bf16* pA = A  + (size_t)(m0 + w * 32 + (lane >> 2)) * kDM + (lane & 3) * 8;
    const bf16* pB = BT + (size_t)(n0 + w * 32 + (lane >> 2)) * kDM + (lane & 3) * 8;
    unsigned short* lA = &At[w * 32][0];
    unsigned short* lB = &Bt[w * 32][0];

    floatx4 acc[4][4];
    #pragma unroll
    for (int i = 0; i < 4; ++i)
        #pragma unroll
        for (int j = 0; j < 4; ++j) acc[i][j] = (floatx4){0.f, 0.f, 0.f, 0.f};

    for (int k0 = 0; k0 < kDM; k0 += 32) {
        __syncthreads();
        gl_lds16(pA + k0, lA);
        gl_lds16(pA + k0 + 16 * kDM, lA + 16 * 32);
        gl_lds16(pB + k0, lB);
        gl_lds16(pB + k0 + 16 * kDM, lB + 16 * 32);
        __syncthreads();
        short8 aA[4], bB[4];
        #pragma unroll
        for (int i = 0; i < 4; ++i)
            aA[i] = *(const short8*)&At[wm * 64 + i * 16 + col][quad * 8];
        #pragma unroll
        for (int j = 0; j < 4; ++j)
            bB[j] = *(const short8*)&Bt[wn * 64 + j * 16 + col][quad * 8];
        #pragma unroll
        for (int i = 0; i < 4; ++i)
            #pragma unroll
            for (int j = 0; j < 4; ++j)
                acc[i][j] = __builtin_amdgcn_mfma_f32_16x16x32_bf16(aA[i], bB[j], acc[i][j], 0, 0, 0);
    }

    const int p  = n0 >> 10;
    const int nn = n0 & 1023;
    const float scl = (p == 0) ? 0.18033688f : 1.0f;   // 0.125 * log2(e)
    bf16* Out = ws + (size_t)p * kHeadElems;
    #pragma unroll
    for (int i = 0; i < 4; ++i) {
        #pragma unroll
        for (int r = 0; r < 4; ++r) {
            const int m = m0 + wm * 64 + i * 16 + quad * 4 + r;
            const int b = m >> 11, s = m & 2047;
            #pragma unroll
            for (int j = 0; j < 4; ++j) {
                const int n = nn + wn * 64 + j * 16 + col;
                const int h = n >> 6, d = n & 63;
                Out[((size_t)(b * kH + h) * kS + s) * kDH + d] = __float2bfloat16(acc[i][j][r] * scl);
            }
        }
    }
}

// ---------------------------------------------------------------------------
// vtrans: V [b,h][2048][64] -> V^T [b,h][64][2048]. grid (32, 64), block 256.
// ---------------------------------------------------------------------------
__global__ __launch_bounds__(256)
void vtrans(const bf16* __restrict__ V, bf16* __restrict__ VT)
{
    const int bh = blockIdx.y;
    const int s0 = blockIdx.x * 64;
    const bf16* src = V + (size_t)bh * kS * kDH;
    bf16* dst = VT + (size_t)bh * kS * kDH;
    __shared__ unsigned short L[64][STR];
    const int tid = threadIdx.x;
    #pragma unroll
    for (int t = 0; t < 2; ++t) {
        const int idx = t * 256 + tid;
        const int r = idx >> 3, c8 = (idx & 7) * 8;
        *(uint4*)&L[r][c8] = *(const uint4*)(src + (size_t)(s0 + r) * kDH + c8);
    }
    __syncthreads();
    #pragma unroll
    for (int t = 0; t < 2; ++t) {
        const int idx = t * 256 + tid;
        const int d = idx >> 3, sc = (idx & 7) * 8;
        unsigned short tmp[8];
        #pragma unroll
        for (int e = 0; e < 8; ++e) tmp[e] = L[sc + e][d];
        *(uint4*)(dst + (size_t)d * kS + s0 + sc) = *(uint4*)tmp;
    }
}

// ---------------------------------------------------------------------------
// attn_mfma v8: round-5 structure, Pw -> per-sub-reused [4][16][64] XOR-swizzled
// (LDS 40960 B exactly -> 4 resident blocks/CU; whole 1024-block grid resident).
// grid (16 qtiles, 64 bh), block 256 = 4 waves x 32 q.
// ---------------------------------------------------------------------------
__global__ __launch_bounds__(256, 4)
void attn_mfma(const bf16* __restrict__ ws, const bf16* __restrict__ VT,
               const unsigned short* __restrict__ EM,
               bf16* __restrict__ Aout)
{
    // XCD-grouped remap: xcd = flat%8 owns bh in [xcd*8, xcd*8+8) -> K+V 4MB = one L2.
    // Same-CU blocks within an XCD have idx strided by 32 -> j strided by 4.
    // qtile(k=j>>2, r=j&3) = 4*(3-k) + ((3-k+r)&3): per-CU qtile sums == 30
    // (balanced 68 tiles/CU), bijective, heavy tiles dispatched first.
    const int flat = blockIdx.x + blockIdx.y * 16;
    const int xcd = flat & 7;
    const int idx = flat >> 3;                 // [0,128)
    const int bh  = xcd * 8 + (idx & 7);
    const int j   = idx >> 3;                  // [0,16)
    const int kk  = 3 - (j >> 2);
    const int qtile = 4 * kk + ((kk + (j & 3)) & 3);
    const int q0 = qtile * 128;

    const int b = bh >> 4, h = bh & 15;
    const int tid  = threadIdx.x;
    const int w    = tid >> 6;
    const int lane = tid & 63;
    const int quad = (tid >> 4) & 3;
    const int col  = tid & 15;

    const size_t ho = (size_t)bh * kS * kDH;
    const bf16* Qg  = ws + ho;                 // pre-scaled by 0.125*log2e
    const bf16* Kg  = ws + kHeadElems + ho;
    const bf16* VTg = VT + ho;                 // [64 d][2048 s]

    __shared__ __align__(16) unsigned short Ks[2][64][64];   // 16 KB, swizzled chunks
    __shared__ __align__(16) unsigned short Vs[2][64][64];   // 16 KB
    __shared__ __align__(16) unsigned short Pw[4][16][64];   // 8 KB, XOR-swizzled

    const int qw = q0 + w * 32;
    const int swz = col & 7;                    // K/V read-side XOR swizzle
    const int sch = (lane & 7) ^ (lane >> 3);   // staging source-chunk swizzle
    const unsigned pswz = (unsigned)(col & 7) << 4;   // Pw byte-XOR swizzle
    char* PwB = (char*)&Pw[w][col][0];          // wave/lane-private row (128 B)

    // Q B-fragments for both 16-row subtiles (n=q=col, k=d)
    short8 bQ[2][2];
    const unsigned short* EMq[2];
    #pragma unroll
    for (int sub = 0; sub < 2; ++sub) {
        const bf16* qrow = Qg + (size_t)(qw + sub * 16 + col) * kDH;
        bQ[sub][0] = *(const short8*)(qrow + quad * 8);
        bQ[sub][1] = *(const short8*)(qrow + 32 + quad * 8);
        EMq[sub] = EM + (size_t)(qw + sub * 16 + col) * kS;
    }

    floatx4 Ov[2][4];
    #pragma unroll
    for (int sub = 0; sub < 2; ++sub)
        #pragma unroll
        for (int dg = 0; dg < 4; ++dg) Ov[sub][dg] = (floatx4){0.f, 0.f, 0.f, 0.f};
    float lacc[2] = {0.f, 0.f};

    const int nt = qtile * 2 + 2;               // block-uniform tile count

    // cooperative stage of tile kt into buffer buf (4 gl_lds per wave)
    auto STAGE = [&](int buf, int kt) {
        const bf16* Kt = Kg  + (size_t)(kt * 64) * kDH;
        const bf16* Vt = VTg + kt * 64;
        #pragma unroll
        for (int t = 0; t < 2; ++t) {
            const int rbase = (t * 4 + w) * 8;
            const int r = rbase + (lane >> 3);
            gl_lds16(Kt + (size_t)r * kDH + sch * 8, &Ks[buf][rbase][0]);
            gl_lds16(Vt + (size_t)r * kS  + sch * 8, &Vs[buf][rbase][0]);
        }
    };

    STAGE(0, 0);
    asm volatile("s_waitcnt vmcnt(0)" ::: "memory");
    __builtin_amdgcn_s_barrier();
    __builtin_amdgcn_sched_barrier(0);

    int cur = 0;
    for (int kt = 0; kt < nt; ++kt) {
        const int kt64 = kt * 64;
        const bool doC = (kt64 <= qw + 31);     // wave-uniform compute guard

        // EM loads for THIS tile, issued BEFORE the new staging loads.
        uint2 em[2][4];
        if (doC) {
            #pragma unroll
            for (int sub = 0; sub < 2; ++sub)
                #pragma unroll
                for (int g = 0; g < 4; ++g)
                    em[sub][g] = *(const uint2*)(EMq[sub] + kt64 + g * 16 + quad * 4);
            __builtin_amdgcn_sched_barrier(0);  // pin EM-issue before STAGE
        }

        if (kt + 1 < nt) STAGE(cur ^ 1, kt + 1);   // depth-1 prefetch

        if (doC) {
            // ---- S^T = K Q^T : A=K rows (LDS), B=Q regs; C: row=key, col=q ----
            floatx4 sg[2][4];
            __builtin_amdgcn_s_setprio(1);
            #pragma unroll
            for (int g = 0; g < 4; ++g) {
                const int krow = g * 16 + col;
                const short8 aK0 = *(const short8*)&Ks[cur][krow][(quad ^ swz) * 8];
                const short8 aK1 = *(const short8*)&Ks[cur][krow][((4 + quad) ^ swz) * 8];
                floatx4 sA = {0.f, 0.f, 0.f, 0.f}, sB = {0.f, 0.f, 0.f, 0.f};
                sA = __builtin_amdgcn_mfma_f32_16x16x32_bf16(aK0, bQ[0][0], sA, 0, 0, 0);
                sA = __builtin_amdgcn_mfma_f32_16x16x32_bf16(aK1, bQ[0][1], sA, 0, 0, 0);
                sB = __builtin_amdgcn_mfma_f32_16x16x32_bf16(aK0, bQ[1][0], sB, 0, 0, 0);
                sB = __builtin_amdgcn_mfma_f32_16x16x32_bf16(aK1, bQ[1][1], sB, 0, 0, 0);
                sg[0][g] = sA; sg[1][g] = sB;
            }
            __builtin_amdgcn_s_setprio(0);

            // ---- per sub: exp2 -> cvt_pk pack -> AND mask -> Pw (swizzled) -> aP ----
            short8 aP[2][2];
            #pragma unroll
            for (int sub = 0; sub < 2; ++sub) {
                const int qbase = qw + sub * 16;
                const bool needC = (kt64 + 63 > qbase);
                float lc = 0.f;
                #pragma unroll
                for (int g = 0; g < 4; ++g) {
                    const float p0 = EXP2(sg[sub][g][0]);
                    const float p1 = EXP2(sg[sub][g][1]);
                    const float p2 = EXP2(sg[sub][g][2]);
                    const float p3 = EXP2(sg[sub][g][3]);
                    if (needC) {
                        const int kb = kt64 + g * 16 + quad * 4;
                        const int qme = qbase + col;
                        lc += (kb + 0 <= qme) ? p0 : 0.f;
                        lc += (kb + 1 <= qme) ? p1 : 0.f;
                        lc += (kb + 2 <= qme) ? p2 : 0.f;
                        lc += (kb + 3 <= qme) ? p3 : 0.f;
                    } else {
                        lc += (p0 + p1) + (p2 + p3);
                    }
                    uint2 pk;
                    pk.x = cvt_pk_bf16(p0, p1) & em[sub][g].x;
                    pk.y = cvt_pk_bf16(p2, p3) & em[sub][g].y;
                    *(uint2*)(PwB + (((unsigned)(g * 32 + quad * 8)) ^ pswz)) = pk;
                }
                lacc[sub] += lc;
                aP[sub][0] = *(const short8*)(PwB + (((unsigned)(quad * 16)) ^ pswz));
                aP[sub][1] = *(const short8*)(PwB + (((unsigned)(64 + quad * 16)) ^ pswz));
            }

            // ---- O += P V : A=P regs, B=V^T rows (LDS) ----
            __builtin_amdgcn_s_setprio(1);
            #pragma unroll
            for (int dg = 0; dg < 4; ++dg) {
                const int vrow = dg * 16 + col;
                const short8 bV0 = *(const short8*)&Vs[cur][vrow][(quad ^ swz) * 8];
                const short8 bV1 = *(const short8*)&Vs[cur][vrow][((4 + quad) ^ swz) * 8];
                Ov[0][dg] = __builtin_amdgcn_mfma_f32_16x16x32_bf16(aP[0][0], bV0, Ov[0][dg], 0, 0, 0);
                Ov[0][dg] = __builtin_amdgcn_mfma_f32_16x16x32_bf16(aP[0][1], bV1, Ov[0][dg], 0, 0, 0);
                Ov[1][dg] = __builtin_amdgcn_mfma_f32_16x16x32_bf16(aP[1][0], bV0, Ov[1][dg], 0, 0, 0);
                Ov[1][dg] = __builtin_amdgcn_mfma_f32_16x16x32_bf16(aP[1][1], bV1, Ov[1][dg], 0, 0, 0);
            }
            __builtin_amdgcn_s_setprio(0);
        }

        asm volatile("s_waitcnt vmcnt(0)" ::: "memory");   // staged tile landed
        __builtin_amdgcn_s_barrier();
        __builtin_amdgcn_sched_barrier(0);
        cur ^= 1;
    }

    // ---- normalize and write ----
    #pragma unroll
    for (int sub = 0; sub < 2; ++sub) {
        float l = lacc[sub];
        l += __shfl_xor(l, 16, 64);
        l += __shfl_xor(l, 32, 64);
        const float linv = 1.f / l;
        #pragma unroll
        for (int r = 0; r < 4; ++r) {
            const float sc = __shfl(linv, quad * 4 + r, 64);
            const int q = qw + sub * 16 + quad * 4 + r;
            bf16* orow = Aout + ((size_t)(b * kS + q)) * kDM + h * kDH;
            #pragma unroll
            for (int dg = 0; dg < 4; ++dg)
                orow[dg * 16 + col] = __float2bfloat16(Ov[sub][dg][r] * sc);
        }
    }
}

// ---------------------------------------------------------------------------
// out_mfma: Aout bf16 @ WoT^T -> fp32 d_out. XCD-local: n-panel per XCD.
// ---------------------------------------------------------------------------
__global__ __launch_bounds__(256)
void out_mfma(const bf16* __restrict__ A, const bf16* __restrict__ BT,
              float* __restrict__ Out)
{
    __shared__ __align__(16) unsigned short At[128][32];
    __shared__ __align__(16) unsigned short Bt[128][32];
    const int tid = threadIdx.x;
    const int w = tid >> 6, lane = tid & 63;
    const int quad = (tid >> 4) & 3, col = tid & 15;
    const int wm = w >> 1, wn = w & 1;
    const int flat = blockIdx.x + blockIdx.y * 8;
    const int n0 = (flat & 7) * 128;
    const int m0 = (flat >> 3) * 128;

    const bf16* pA = A  + (size_t)(m0 + w * 32 + (lane >> 2)) * kDM + (lane & 3) * 8;
    const bf16* pB = BT + (size_t)(n0 + w * 32 + (lane >> 2)) * kDM + (lane & 3) * 8;
    unsigned short* lA = &At[w * 32][0];
    unsigned short* lB = &Bt[w * 32][0];

    floatx4 acc[4][4];
    #pragma unroll
    for (int i = 0; i < 4; ++i)
        #pragma unroll
        for (int j = 0; j < 4; ++j) acc[i][j] = (floatx4){0.f, 0.f, 0.f, 0.f};

    for (int k0 = 0; k0 < kDM; k0 += 32) {
        __syncthreads();
        gl_lds16(pA + k0, lA);
        gl_lds16(pA + k0 + 16 * kDM, lA + 16 * 32);
        gl_lds16(pB + k0, lB);
        gl_lds16(pB + k0 + 16 * kDM, lB + 16 * 32);
        __syncthreads();
        short8 aA[4], bB[4];
        #pragma unroll
        for (int i = 0; i < 4; ++i)
            aA[i] = *(const short8*)&At[wm * 64 + i * 16 + col][quad * 8];
        #pragma unroll
        for (int j = 0; j < 4; ++j)
            bB[j] = *(const short8*)&Bt[wn * 64 + j * 16 + col][quad * 8];
        #pragma unroll
        for (int i = 0; i < 4; ++i)
            #pragma unroll
            for (int j = 0; j < 4; ++j)
                acc[i][j] = __builtin_amdgcn_mfma_f32_16x16x32_bf16(aA[i], bB[j], acc[i][j], 0, 0, 0);
    }

    #pragma unroll
    for (int i = 0; i < 4; ++i)
        #pragma unroll
        for (int r = 0; r < 4; ++r) {
            const int m = m0 + wm * 64 + i * 16 + quad * 4 + r;
            #pragma unroll
            for (int j = 0; j < 4; ++j)
                Out[(size_t)m * kDM + n0 + wn * 64 + j * 16 + col] = acc[i][j][r];
        }
}

// ---------------------------------------------------------------------------
extern "C" void kernel_launch(void* const* d_in, const int* in_sizes, int n_in,
                              void* d_out, int out_size, void* d_ws, size_t ws_size,
                              hipStream_t stream)
{
    const float* Xq       = (const float*)d_in[0];
    // d_in[1] = mask_bef (causal, analytic — unused)
    const int*   mask_aft = (const int*)d_in[2];
    const float* Wq       = (const float*)d_in[3];
    const float* Wk       = (const float*)d_in[4];
    const float* Wv       = (const float*)d_in[5];
    const float* Wo       = (const float*)d_in[6];
    float* out = (float*)d_out;

    bf16* ws   = (bf16*)d_ws;
    bf16* Xbf  = ws + 3 * kHeadElems;      // aliased: Xbf (qkv input) -> Aout (attn output)
    bf16* Aout = Xbf;
    bf16* WoT  = ws;                       // overwrites Q slot AFTER attn

    bf16* WcatT = (bf16*)d_out + 262144;                                   // +512KB, 6MB
    bf16* VT    = (bf16*)((char*)d_out + 8u * 1024 * 1024);                // +8MB, 16MB
    unsigned short* EMp = (unsigned short*)((char*)d_out + 24u * 1024 * 1024); // +24MB, 8MB

    fused_pre<<<dim3(6144), 256, 0, stream>>>(Xq, Xbf, mask_aft, EMp);
    conv_w3 <<<dim3(16, 16, 3), 256, 0, stream>>>(Wq, Wk, Wv, WcatT);
    qkv_mfma<<<dim3(24, 64), 256, 0, stream>>>(Xbf, WcatT, ws);
    vtrans  <<<dim3(32, 64), 256, 0, stream>>>(ws + 2 * kHeadElems, VT);
    attn_mfma<<<dim3(16, 64), 256, 0, stream>>>(ws, VT, EMp, Aout);
    conv_wT <<<dim3(16, 16), 256, 0, stream>>>(Wo, WoT);          // Q slot now dead
    out_mfma<<<dim3(8, 64), 256, 0, stream>>>(Aout, WoT, out);
}

// Round 7
// 336.112 us; speedup vs baseline: 1.1055x; 1.1055x over previous
//
#include <hip/hip_runtime.h>
#include <hip/hip_bf16.h>

// Attention round 10: round-5 attn (best measured, 98.9us) + pipelined GEMMs.
//  - attn_mfma: exact round-5 config (128-q blocks, 4 waves x 32 q, balanced
//    per-CU qtile map, 2-buffer depth-1 prefetch, Pw[4][2][16][72], LDS 51200,
//    3 blocks/CU). Round-6's Pw-shrink/4-block variant regressed — reverted.
//  - qkv_mfma / out_mfma: double-buffered LDS + depth-1 prefetch, ONE
//    vmcnt(0)+s_barrier per K-step (was: barrier -> stage -> barrier, a full
//    drain-stall per iter — same defect round 2 fixed in attn).
//  - fused_pre (conv_x+pack_em), conv_w3 (Wq/Wk/Wv) launch fusions kept.
// B=4 S=2048 D=1024 H=16 d=64.
// ws (bf16): Q(prescaled) | K | V | {Xbf -> Aout}; WoT overwrites Q slot after attn.
// d_out temp: WcatT @ +512KB (6MB) | V^T @ +8MB (16MB) | EM @ +24MB (8MB).

using bf16 = __hip_bfloat16;
typedef __attribute__((ext_vector_type(8))) short short8;
typedef __attribute__((ext_vector_type(4))) float floatx4;

#define kB 4
#define kS 2048
#define kDM 1024
#define kH 16
#define kDH 64
#define kHeadElems ((size_t)kB * kH * kS * kDH)   /* 8388608 */
#define STR 72

#if __has_builtin(__builtin_amdgcn_exp2f)
#define EXP2(x) __builtin_amdgcn_exp2f(x)
#else
#define EXP2(x) __expf((x) * 0.69314718056f)
#endif

__device__ __forceinline__ unsigned short f2bf(float f) {
    union { float f; unsigned u; } x{f};
    unsigned r = x.u + 0x7fff + ((x.u >> 16) & 1);
    return (unsigned short)(r >> 16);
}
__device__ __forceinline__ unsigned cvt_pk_bf16(float lo, float hi) {
    unsigned r;
    asm("v_cvt_pk_bf16_f32 %0, %1, %2" : "=v"(r) : "v"(lo), "v"(hi));
    return r;
}
__device__ __forceinline__ void gl_lds16(const void* g, void* l) {
    __builtin_amdgcn_global_load_lds(
        (const __attribute__((address_space(1))) unsigned int*)g,
        (__attribute__((address_space(3))) unsigned int*)l, 16, 0, 0);
}

// ---------------------------------------------------------------------------
// fused_pre: blocks [0,4096) = conv_x; blocks [4096,6144) = pack_em.
// ---------------------------------------------------------------------------
__global__ __launch_bounds__(256)
void fused_pre(const float* __restrict__ X, bf16* __restrict__ Xb,
               const int* __restrict__ mask_aft, unsigned short* __restrict__ EM)
{
    const int bid = blockIdx.x;
    if (bid < 4096) {
        const size_t i = ((size_t)bid * 256 + threadIdx.x) * 8;
        const float4 a = *(const float4*)(X + i);
        const float4 b = *(const float4*)(X + i + 4);
        union { unsigned short u[8]; uint4 v; } o;
        o.u[0] = f2bf(a.x); o.u[1] = f2bf(a.y); o.u[2] = f2bf(a.z); o.u[3] = f2bf(a.w);
        o.u[4] = f2bf(b.x); o.u[5] = f2bf(b.y); o.u[6] = f2bf(b.z); o.u[7] = f2bf(b.w);
        *(uint4*)(Xb + i) = o.v;
    } else {
        const size_t i = ((size_t)(bid - 4096) * 256 + threadIdx.x) * 8;
        const int q  = (int)(i >> 11);
        const int k0 = (int)(i & 2047);
        const int4 m0 = *(const int4*)(mask_aft + i);
        const int4 m1 = *(const int4*)(mask_aft + i + 4);
        union { unsigned short u[8]; uint4 v; } o;
        o.u[0] = (m0.x || (k0 + 0) > q) ? 0 : 0xFFFFu;
        o.u[1] = (m0.y || (k0 + 1) > q) ? 0 : 0xFFFFu;
        o.u[2] = (m0.z || (k0 + 2) > q) ? 0 : 0xFFFFu;
        o.u[3] = (m0.w || (k0 + 3) > q) ? 0 : 0xFFFFu;
        o.u[4] = (m1.x || (k0 + 4) > q) ? 0 : 0xFFFFu;
        o.u[5] = (m1.y || (k0 + 5) > q) ? 0 : 0xFFFFu;
        o.u[6] = (m1.z || (k0 + 6) > q) ? 0 : 0xFFFFu;
        o.u[7] = (m1.w || (k0 + 7) > q) ? 0 : 0xFFFFu;
        *(uint4*)(EM + i) = o.v;
    }
}

// ---------------------------------------------------------------------------
// conv_w3: W [1024][1024] fp32 -> W^T bf16, z selects Wq/Wk/Wv.
// ---------------------------------------------------------------------------
__global__ __launch_bounds__(256)
void conv_w3(const float* __restrict__ Wq, const float* __restrict__ Wk,
             const float* __restrict__ Wv, bf16* __restrict__ WT)
{
    const float* W = (blockIdx.z == 0) ? Wq : (blockIdx.z == 1) ? Wk : Wv;
    bf16* dst = WT + (size_t)blockIdx.z * kDM * kDM;
    __shared__ unsigned short Ls[64][STR];
    const int k0 = blockIdx.x * 64, n0 = blockIdx.y * 64;
    const int tid = threadIdx.x;
    const int r16 = tid >> 4, c4 = (tid & 15) * 4;
    #pragma unroll
    for (int it = 0; it < 4; ++it) {
        const int r = it * 16 + r16;
        const float4 v = *(const float4*)(W + (size_t)(k0 + r) * kDM + n0 + c4);
        Ls[c4 + 0][r] = f2bf(v.x); Ls[c4 + 1][r] = f2bf(v.y);
        Ls[c4 + 2][r] = f2bf(v.z); Ls[c4 + 3][r] = f2bf(v.w);
    }
    __syncthreads();
    #pragma unroll
    for (int it = 0; it < 4; ++it) {
        const int rn = it * 16 + r16;
        ushort4 u;
        u.x = Ls[rn][c4 + 0]; u.y = Ls[rn][c4 + 1];
        u.z = Ls[rn][c4 + 2]; u.w = Ls[rn][c4 + 3];
        *(ushort4*)(dst + (size_t)(n0 + rn) * kDM + k0 + c4) = u;
    }
}

// ---------------------------------------------------------------------------
// conv_wT: single W transpose (Wo, after attn frees the Q slot).
// ---------------------------------------------------------------------------
__global__ __launch_bounds__(256)
void conv_wT(const float* __restrict__ W, bf16* __restrict__ WT)
{
    __shared__ unsigned short Ls[64][STR];
    const int k0 = blockIdx.x * 64, n0 = blockIdx.y * 64;
    const int tid = threadIdx.x;
    const int r16 = tid >> 4, c4 = (tid & 15) * 4;
    #pragma unroll
    for (int it = 0; it < 4; ++it) {
        const int r = it * 16 + r16;
        const float4 v = *(const float4*)(W + (size_t)(k0 + r) * kDM + n0 + c4);
        Ls[c4 + 0][r] = f2bf(v.x); Ls[c4 + 1][r] = f2bf(v.y);
        Ls[c4 + 2][r] = f2bf(v.z); Ls[c4 + 3][r] = f2bf(v.w);
    }
    __syncthreads();
    #pragma unroll
    for (int it = 0; it < 4; ++it) {
        const int rn = it * 16 + r16;
        ushort4 u;
        u.x = Ls[rn][c4 + 0]; u.y = Ls[rn][c4 + 1];
        u.z = Ls[rn][c4 + 2]; u.w = Ls[rn][c4 + 3];
        *(ushort4*)(WT + (size_t)(n0 + rn) * kDM + k0 + c4) = u;
    }
}

// ---------------------------------------------------------------------------
// qkv_mfma v2: A[8192][1024] @ WcatT[3072][1024]^T, double-buffered LDS,
// depth-1 prefetch, ONE vmcnt(0)+s_barrier per K-step. XCD-local swizzle.
// Q pre-scaled by 0.125*log2(e).
// ---------------------------------------------------------------------------
__global__ __launch_bounds__(256)
void qkv_mfma(const bf16* __restrict__ A, const bf16* __restrict__ BT,
              bf16* __restrict__ ws)
{
    __shared__ __align__(16) unsigned short At[2][128][32];
    __shared__ __align__(16) unsigned short Bt[2][128][32];
    const int tid = threadIdx.x;
    const int w = tid >> 6, lane = tid & 63;
    const int quad = (tid >> 4) & 3, col = tid & 15;
    const int wm = w >> 1, wn = w & 1;
    const int flat = blockIdx.x + blockIdx.y * 24;
    const int xcd = flat & 7;
    const int i2 = flat >> 3;                  // [0,192)
    const int n0 = (xcd * 3 + (i2 % 3)) * 128;
    const int m0 = (i2 / 3) * 128;

    const bf16* pA = A  + (size_t)(m0 + w * 32 + (lane >> 2)) * kDM + (lane & 3) * 8;
    const bf16* pB = BT + (size_t)(n0 + w * 32 + (lane >> 2)) * kDM + (lane & 3) * 8;

    floatx4 acc[4][4];
    #pragma unroll
    for (int i = 0; i < 4; ++i)
        #pragma unroll
        for (int j = 0; j < 4; ++j) acc[i][j] = (floatx4){0.f, 0.f, 0.f, 0.f};

    auto STAGE = [&](int buf, int k0) {
        gl_lds16(pA + k0, &At[buf][w * 32][0]);
        gl_lds16(pA + k0 + 16 * kDM, &At[buf][w * 32 + 16][0]);
        gl_lds16(pB + k0, &Bt[buf][w * 32][0]);
        gl_lds16(pB + k0 + 16 * kDM, &Bt[buf][w * 32 + 16][0]);
    };

    STAGE(0, 0);
    asm volatile("s_waitcnt vmcnt(0)" ::: "memory");
    __builtin_amdgcn_s_barrier();
    __builtin_amdgcn_sched_barrier(0);

    int cur = 0;
    for (int k0 = 0; k0 < kDM; k0 += 32) {
        if (k0 + 32 < kDM) STAGE(cur ^ 1, k0 + 32);   // issue next tile first
        short8 aA[4], bB[4];
        #pragma unroll
        for (int i = 0; i < 4; ++i)
            aA[i] = *(const short8*)&At[cur][wm * 64 + i * 16 + col][quad * 8];
        #pragma unroll
        for (int j = 0; j < 4; ++j)
            bB[j] = *(const short8*)&Bt[cur][wn * 64 + j * 16 + col][quad * 8];
        #pragma unroll
        for (int i = 0; i < 4; ++i)
            #pragma unroll
            for (int j = 0; j < 4; ++j)
                acc[i][j] = __builtin_amdgcn_mfma_f32_16x16x32_bf16(aA[i], bB[j], acc[i][j], 0, 0, 0);
        asm volatile("s_waitcnt vmcnt(0)" ::: "memory");
        __builtin_amdgcn_s_barrier();
        __builtin_amdgcn_sched_barrier(0);
        cur ^= 1;
    }

    const int p  = n0 >> 10;
    const int nn = n0 & 1023;
    const float scl = (p == 0) ? 0.18033688f : 1.0f;   // 0.125 * log2(e)
    bf16* Out = ws + (size_t)p * kHeadElems;
    #pragma unroll
    for (int i = 0; i < 4; ++i) {
        #pragma unroll
        for (int r = 0; r < 4; ++r) {
            const int m = m0 + wm * 64 + i * 16 + quad * 4 + r;
            const int b = m >> 11, s = m & 2047;
            #pragma unroll
            for (int j = 0; j < 4; ++j) {
                const int n = nn + wn * 64 + j * 16 + col;
                const int h = n >> 6, d = n & 63;
                Out[((size_t)(b * kH + h) * kS + s) * kDH + d] = __float2bfloat16(acc[i][j][r] * scl);
            }
        }
    }
}

// ---------------------------------------------------------------------------
// vtrans: V [b,h][2048][64] -> V^T [b,h][64][2048]. grid (32, 64), block 256.
// ---------------------------------------------------------------------------
__global__ __launch_bounds__(256)
void vtrans(const bf16* __restrict__ V, bf16* __restrict__ VT)
{
    const int bh = blockIdx.y;
    const int s0 = blockIdx.x * 64;
    const bf16* src = V + (size_t)bh * kS * kDH;
    bf16* dst = VT + (size_t)bh * kS * kDH;
    __shared__ unsigned short L[64][STR];
    const int tid = threadIdx.x;
    #pragma unroll
    for (int t = 0; t < 2; ++t) {
        const int idx = t * 256 + tid;
        const int r = idx >> 3, c8 = (idx & 7) * 8;
        *(uint4*)&L[r][c8] = *(const uint4*)(src + (size_t)(s0 + r) * kDH + c8);
    }
    __syncthreads();
    #pragma unroll
    for (int t = 0; t < 2; ++t) {
        const int idx = t * 256 + tid;
        const int d = idx >> 3, sc = (idx & 7) * 8;
        unsigned short tmp[8];
        #pragma unroll
        for (int e = 0; e < 8; ++e) tmp[e] = L[sc + e][d];
        *(uint4*)(dst + (size_t)d * kS + s0 + sc) = *(uint4*)tmp;
    }
}

// ---------------------------------------------------------------------------
// attn_mfma v7 (round-5, best measured): balanced qtile map + 2-buffer depth-1
// pipeline, 3 blocks/CU. grid (16 qtiles, 64 bh), block 256 = 4 waves x 32 q.
// ---------------------------------------------------------------------------
__global__ __launch_bounds__(256, 3)
void attn_mfma(const bf16* __restrict__ ws, const bf16* __restrict__ VT,
               const unsigned short* __restrict__ EM,
               bf16* __restrict__ Aout)
{
    // XCD-grouped remap: xcd = flat%8 owns bh in [xcd*8, xcd*8+8) -> K+V 4MB = one L2.
    // qtile(k=j>>2, r=j&3) = 4*(3-k) + ((3-k+r)&3): per-CU qtile sums == 30
    // (balanced 68 tiles/CU), bijective, heavy tiles dispatched first.
    const int flat = blockIdx.x + blockIdx.y * 16;
    const int xcd = flat & 7;
    const int idx = flat >> 3;                 // [0,128)
    const int bh  = xcd * 8 + (idx & 7);
    const int j   = idx >> 3;                  // [0,16)
    const int kk  = 3 - (j >> 2);
    const int qtile = 4 * kk + ((kk + (j & 3)) & 3);
    const int q0 = qtile * 128;

    const int b = bh >> 4, h = bh & 15;
    const int tid  = threadIdx.x;
    const int w    = tid >> 6;
    const int lane = tid & 63;
    const int quad = (tid >> 4) & 3;
    const int col  = tid & 15;

    const size_t ho = (size_t)bh * kS * kDH;
    const bf16* Qg  = ws + ho;                 // pre-scaled by 0.125*log2e
    const bf16* Kg  = ws + kHeadElems + ho;
    const bf16* VTg = VT + ho;                 // [64 d][2048 s]

    __shared__ __align__(16) unsigned short Ks[2][64][64];   // XOR-swizzled chunks
    __shared__ __align__(16) unsigned short Vs[2][64][64];
    __shared__ __align__(16) unsigned short Pw[4][2][16][STR];

    const int qw = q0 + w * 32;
    const int swz = col & 7;                    // read-side XOR swizzle
    const int sch = (lane & 7) ^ (lane >> 3);   // staging source-chunk swizzle

    // Q B-fragments for both 16-row subtiles (n=q=col, k=d)
    short8 bQ[2][2];
    const unsigned short* EMq[2];
    #pragma unroll
    for (int sub = 0; sub < 2; ++sub) {
        const bf16* qrow = Qg + (size_t)(qw + sub * 16 + col) * kDH;
        bQ[sub][0] = *(const short8*)(qrow + quad * 8);
        bQ[sub][1] = *(const short8*)(qrow + 32 + quad * 8);
        EMq[sub] = EM + (size_t)(qw + sub * 16 + col) * kS;
    }

    floatx4 Ov[2][4];
    #pragma unroll
    for (int sub = 0; sub < 2; ++sub)
        #pragma unroll
        for (int dg = 0; dg < 4; ++dg) Ov[sub][dg] = (floatx4){0.f, 0.f, 0.f, 0.f};
    float lacc[2] = {0.f, 0.f};

    const int nt = qtile * 2 + 2;               // block-uniform tile count

    // cooperative stage of tile kt into buffer buf (4 gl_lds per wave)
    auto STAGE = [&](int buf, int kt) {
        const bf16* Kt = Kg  + (size_t)(kt * 64) * kDH;
        const bf16* Vt = VTg + kt * 64;
        #pragma unroll
        for (int t = 0; t < 2; ++t) {
            const int rbase = (t * 4 + w) * 8;
            const int r = rbase + (lane >> 3);
            gl_lds16(Kt + (size_t)r * kDH + sch * 8, &Ks[buf][rbase][0]);
            gl_lds16(Vt + (size_t)r * kS  + sch * 8, &Vs[buf][rbase][0]);
        }
    };

    STAGE(0, 0);
    asm volatile("s_waitcnt vmcnt(0)" ::: "memory");
    __builtin_amdgcn_s_barrier();
    __builtin_amdgcn_sched_barrier(0);

    int cur = 0;
    for (int kt = 0; kt < nt; ++kt) {
        const int kt64 = kt * 64;
        const bool doC = (kt64 <= qw + 31);     // wave-uniform compute guard

        // EM loads for THIS tile, issued BEFORE the new staging loads.
        uint2 em[2][4];
        if (doC) {
            #pragma unroll
            for (int sub = 0; sub < 2; ++sub)
                #pragma unroll
                for (int g = 0; g < 4; ++g)
                    em[sub][g] = *(const uint2*)(EMq[sub] + kt64 + g * 16 + quad * 4);
            __builtin_amdgcn_sched_barrier(0);  // pin EM-issue before STAGE
        }

        if (kt + 1 < nt) STAGE(cur ^ 1, kt + 1);   // depth-1 prefetch

        if (doC) {
            // ---- S^T = K Q^T : A=K rows (LDS), B=Q regs; C: row=key, col=q ----
            floatx4 sg[2][4];
            __builtin_amdgcn_s_setprio(1);
            #pragma unroll
            for (int g = 0; g < 4; ++g) {
                const int krow = g * 16 + col;
                const short8 aK0 = *(const short8*)&Ks[cur][krow][(quad ^ swz) * 8];
                const short8 aK1 = *(const short8*)&Ks[cur][krow][((4 + quad) ^ swz) * 8];
                floatx4 sA = {0.f, 0.f, 0.f, 0.f}, sB = {0.f, 0.f, 0.f, 0.f};
                sA = __builtin_amdgcn_mfma_f32_16x16x32_bf16(aK0, bQ[0][0], sA, 0, 0, 0);
                sA = __builtin_amdgcn_mfma_f32_16x16x32_bf16(aK1, bQ[0][1], sA, 0, 0, 0);
                sB = __builtin_amdgcn_mfma_f32_16x16x32_bf16(aK0, bQ[1][0], sB, 0, 0, 0);
                sB = __builtin_amdgcn_mfma_f32_16x16x32_bf16(aK1, bQ[1][1], sB, 0, 0, 0);
                sg[0][g] = sA; sg[1][g] = sB;
            }
            __builtin_amdgcn_s_setprio(0);

            // ---- softmax numerator (exp2), cvt_pk pack, AND expanded mask ----
            #pragma unroll
            for (int sub = 0; sub < 2; ++sub) {
                const int qbase = qw + sub * 16;
                const bool needC = (kt64 + 63 > qbase);
                float lc = 0.f;
                #pragma unroll
                for (int g = 0; g < 4; ++g) {
                    const float p0 = EXP2(sg[sub][g][0]);
                    const float p1 = EXP2(sg[sub][g][1]);
                    const float p2 = EXP2(sg[sub][g][2]);
                    const float p3 = EXP2(sg[sub][g][3]);
                    if (needC) {
                        const int kb = kt64 + g * 16 + quad * 4;
                        const int qme = qbase + col;
                        lc += (kb + 0 <= qme) ? p0 : 0.f;
                        lc += (kb + 1 <= qme) ? p1 : 0.f;
                        lc += (kb + 2 <= qme) ? p2 : 0.f;
                        lc += (kb + 3 <= qme) ? p3 : 0.f;
                    } else {
                        lc += (p0 + p1) + (p2 + p3);
                    }
                    uint2 pk;
                    pk.x = cvt_pk_bf16(p0, p1) & em[sub][g].x;
                    pk.y = cvt_pk_bf16(p2, p3) & em[sub][g].y;
                    *(uint2*)&Pw[w][sub][col][g * 16 + quad * 4] = pk;
                }
                lacc[sub] += lc;
            }

            // ---- O += P V : A=P (wave-private LDS), B=V^T rows (LDS) ----
            const short8 aP[2][2] = {
                { *(const short8*)&Pw[w][0][col][quad * 8],
                  *(const short8*)&Pw[w][0][col][32 + quad * 8] },
                { *(const short8*)&Pw[w][1][col][quad * 8],
                  *(const short8*)&Pw[w][1][col][32 + quad * 8] } };
            __builtin_amdgcn_s_setprio(1);
            #pragma unroll
            for (int dg = 0; dg < 4; ++dg) {
                const int vrow = dg * 16 + col;
                const short8 bV0 = *(const short8*)&Vs[cur][vrow][(quad ^ swz) * 8];
                const short8 bV1 = *(const short8*)&Vs[cur][vrow][((4 + quad) ^ swz) * 8];
                Ov[0][dg] = __builtin_amdgcn_mfma_f32_16x16x32_bf16(aP[0][0], bV0, Ov[0][dg], 0, 0, 0);
                Ov[0][dg] = __builtin_amdgcn_mfma_f32_16x16x32_bf16(aP[0][1], bV1, Ov[0][dg], 0, 0, 0);
                Ov[1][dg] = __builtin_amdgcn_mfma_f32_16x16x32_bf16(aP[1][0], bV0, Ov[1][dg], 0, 0, 0);
                Ov[1][dg] = __builtin_amdgcn_mfma_f32_16x16x32_bf16(aP[1][1], bV1, Ov[1][dg], 0, 0, 0);
            }
            __builtin_amdgcn_s_setprio(0);
        }

        asm volatile("s_waitcnt vmcnt(0)" ::: "memory");   // staged tile landed
        __builtin_amdgcn_s_barrier();
        __builtin_amdgcn_sched_barrier(0);
        cur ^= 1;
    }

    // ---- normalize and write ----
    #pragma unroll
    for (int sub = 0; sub < 2; ++sub) {
        float l = lacc[sub];
        l += __shfl_xor(l, 16, 64);
        l += __shfl_xor(l, 32, 64);
        const float linv = 1.f / l;
        #pragma unroll
        for (int r = 0; r < 4; ++r) {
            const float sc = __shfl(linv, quad * 4 + r, 64);
            const int q = qw + sub * 16 + quad * 4 + r;
            bf16* orow = Aout + ((size_t)(b * kS + q)) * kDM + h * kDH;
            #pragma unroll
            for (int dg = 0; dg < 4; ++dg)
                orow[dg * 16 + col] = __float2bfloat16(Ov[sub][dg][r] * sc);
        }
    }
}

// ---------------------------------------------------------------------------
// out_mfma v2: Aout bf16 @ WoT^T -> fp32, double-buffered depth-1 pipeline.
// XCD-local: n-panel per XCD.
// ---------------------------------------------------------------------------
__global__ __launch_bounds__(256)
void out_mfma(const bf16* __restrict__ A, const bf16* __restrict__ BT,
              float* __restrict__ Out)
{
    __shared__ __align__(16) unsigned short At[2][128][32];
    __shared__ __align__(16) unsigned short Bt[2][128][32];
    const int tid = threadIdx.x;
    const int w = tid >> 6, lane = tid & 63;
    const int quad = (tid >> 4) & 3, col = tid & 15;
    const int wm = w >> 1, wn = w & 1;
    const int flat = blockIdx.x + blockIdx.y * 8;
    const int n0 = (flat & 7) * 128;
    const int m0 = (flat >> 3) * 128;

    const bf16* pA = A  + (size_t)(m0 + w * 32 + (lane >> 2)) * kDM + (lane & 3) * 8;
    const bf16* pB = BT + (size_t)(n0 + w * 32 + (lane >> 2)) * kDM + (lane & 3) * 8;

    floatx4 acc[4][4];
    #pragma unroll
    for (int i = 0; i < 4; ++i)
        #pragma unroll
        for (int j = 0; j < 4; ++j) acc[i][j] = (floatx4){0.f, 0.f, 0.f, 0.f};

    auto STAGE = [&](int buf, int k0) {
        gl_lds16(pA + k0, &At[buf][w * 32][0]);
        gl_lds16(pA + k0 + 16 * kDM, &At[buf][w * 32 + 16][0]);
        gl_lds16(pB + k0, &Bt[buf][w * 32][0]);
        gl_lds16(pB + k0 + 16 * kDM, &Bt[buf][w * 32 + 16][0]);
    };

    STAGE(0, 0);
    asm volatile("s_waitcnt vmcnt(0)" ::: "memory");
    __builtin_amdgcn_s_barrier();
    __builtin_amdgcn_sched_barrier(0);

    int cur = 0;
    for (int k0 = 0; k0 < kDM; k0 += 32) {
        if (k0 + 32 < kDM) STAGE(cur ^ 1, k0 + 32);
        short8 aA[4], bB[4];
        #pragma unroll
        for (int i = 0; i < 4; ++i)
            aA[i] = *(const short8*)&At[cur][wm * 64 + i * 16 + col][quad * 8];
        #pragma unroll
        for (int j = 0; j < 4; ++j)
            bB[j] = *(const short8*)&Bt[cur][wn * 64 + j * 16 + col][quad * 8];
        #pragma unroll
        for (int i = 0; i < 4; ++i)
            #pragma unroll
            for (int j = 0; j < 4; ++j)
                acc[i][j] = __builtin_amdgcn_mfma_f32_16x16x32_bf16(aA[i], bB[j], acc[i][j], 0, 0, 0);
        asm volatile("s_waitcnt vmcnt(0)" ::: "memory");
        __builtin_amdgcn_s_barrier();
        __builtin_amdgcn_sched_barrier(0);
        cur ^= 1;
    }

    #pragma unroll
    for (int i = 0; i < 4; ++i)
        #pragma unroll
        for (int r = 0; r < 4; ++r) {
            const int m = m0 + wm * 64 + i * 16 + quad * 4 + r;
            #pragma unroll
            for (int j = 0; j < 4; ++j)
                Out[(size_t)m * kDM + n0 + wn * 64 + j * 16 + col] = acc[i][j][r];
        }
}

// ---------------------------------------------------------------------------
extern "C" void kernel_launch(void* const* d_in, const int* in_sizes, int n_in,
                              void* d_out, int out_size, void* d_ws, size_t ws_size,
                              hipStream_t stream)
{
    const float* Xq       = (const float*)d_in[0];
    // d_in[1] = mask_bef (causal, analytic — unused)
    const int*   mask_aft = (const int*)d_in[2];
    const float* Wq       = (const float*)d_in[3];
    const float* Wk       = (const float*)d_in[4];
    const float* Wv       = (const float*)d_in[5];
    const float* Wo       = (const float*)d_in[6];
    float* out = (float*)d_out;

    bf16* ws   = (bf16*)d_ws;
    bf16* Xbf  = ws + 3 * kHeadElems;      // aliased: Xbf (qkv input) -> Aout (attn output)
    bf16* Aout = Xbf;
    bf16* WoT  = ws;                       // overwrites Q slot AFTER attn

    bf16* WcatT = (bf16*)d_out + 262144;                                   // +512KB, 6MB
    bf16* VT    = (bf16*)((char*)d_out + 8u * 1024 * 1024);                // +8MB, 16MB
    unsigned short* EMp = (unsigned short*)((char*)d_out + 24u * 1024 * 1024); // +24MB, 8MB

    fused_pre<<<dim3(6144), 256, 0, stream>>>(Xq, Xbf, mask_aft, EMp);
    conv_w3 <<<dim3(16, 16, 3), 256, 0, stream>>>(Wq, Wk, Wv, WcatT);
    qkv_mfma<<<dim3(24, 64), 256, 0, stream>>>(Xbf, WcatT, ws);
    vtrans  <<<dim3(32, 64), 256, 0, stream>>>(ws + 2 * kHeadElems, VT);
    attn_mfma<<<dim3(16, 64), 256, 0, stream>>>(ws, VT, EMp, Aout);
    conv_wT <<<dim3(16, 16), 256, 0, stream>>>(Wo, WoT);          // Q slot now dead
    out_mfma<<<dim3(8, 64), 256, 0, stream>>>(Aout, WoT, out);
}

// Round 8
// 322.005 us; speedup vs baseline: 1.1540x; 1.0438x over previous
//
#include <hip/hip_runtime.h>
#include <hip/hip_bf16.h>

// Attention round 11: round-5 proven kernels + structural dispatch elimination.
//  - attn_mfma: EXACT round-5/7 config (measured best, ~98us): 128-q blocks,
//    4 waves x 32 q, balanced per-CU qtile map, 2-buffer depth-1 prefetch,
//    LDS 51200, 3 blocks/CU.
//  - qkv/out GEMMs: round-5 single-buffer form (r7's dbuf halved occupancy,
//    -13us net — reverted). qkv gains a V-transpose epilogue: p==2 panels
//    write acc through a 16KB XOR-swizzled LDS transpose straight to
//    VT[bh][64][2048] (coalesced) — vtrans kernel deleted.
//  - conv_w4: Wq/Wk/Wv -> WcatT and Wo -> ws V-slot (free now) in ONE launch.
//  - 5 dispatches total (was 7).
// B=4 S=2048 D=1024 H=16 d=64.
// ws (bf16): Q(prescaled) | K | WoT | {Xbf -> Aout}.
// d_out temp: WcatT @ +512KB (6MB) | V^T @ +8MB (16MB) | EM @ +24MB (8MB).

using bf16 = __hip_bfloat16;
typedef __attribute__((ext_vector_type(8))) short short8;
typedef __attribute__((ext_vector_type(4))) float floatx4;

#define kB 4
#define kS 2048
#define kDM 1024
#define kH 16
#define kDH 64
#define kHeadElems ((size_t)kB * kH * kS * kDH)   /* 8388608 */
#define STR 72

#if __has_builtin(__builtin_amdgcn_exp2f)
#define EXP2(x) __builtin_amdgcn_exp2f(x)
#else
#define EXP2(x) __expf((x) * 0.69314718056f)
#endif

__device__ __forceinline__ unsigned short f2bf(float f) {
    union { float f; unsigned u; } x{f};
    unsigned r = x.u + 0x7fff + ((x.u >> 16) & 1);
    return (unsigned short)(r >> 16);
}
__device__ __forceinline__ unsigned cvt_pk_bf16(float lo, float hi) {
    unsigned r;
    asm("v_cvt_pk_bf16_f32 %0, %1, %2" : "=v"(r) : "v"(lo), "v"(hi));
    return r;
}
__device__ __forceinline__ void gl_lds16(const void* g, void* l) {
    __builtin_amdgcn_global_load_lds(
        (const __attribute__((address_space(1))) unsigned int*)g,
        (__attribute__((address_space(3))) unsigned int*)l, 16, 0, 0);
}

// ---------------------------------------------------------------------------
// fused_pre: blocks [0,4096) = conv_x; blocks [4096,6144) = pack_em.
// ---------------------------------------------------------------------------
__global__ __launch_bounds__(256)
void fused_pre(const float* __restrict__ X, bf16* __restrict__ Xb,
               const int* __restrict__ mask_aft, unsigned short* __restrict__ EM)
{
    const int bid = blockIdx.x;
    if (bid < 4096) {
        const size_t i = ((size_t)bid * 256 + threadIdx.x) * 8;
        const float4 a = *(const float4*)(X + i);
        const float4 b = *(const float4*)(X + i + 4);
        union { unsigned short u[8]; uint4 v; } o;
        o.u[0] = f2bf(a.x); o.u[1] = f2bf(a.y); o.u[2] = f2bf(a.z); o.u[3] = f2bf(a.w);
        o.u[4] = f2bf(b.x); o.u[5] = f2bf(b.y); o.u[6] = f2bf(b.z); o.u[7] = f2bf(b.w);
        *(uint4*)(Xb + i) = o.v;
    } else {
        const size_t i = ((size_t)(bid - 4096) * 256 + threadIdx.x) * 8;
        const int q  = (int)(i >> 11);
        const int k0 = (int)(i & 2047);
        const int4 m0 = *(const int4*)(mask_aft + i);
        const int4 m1 = *(const int4*)(mask_aft + i + 4);
        union { unsigned short u[8]; uint4 v; } o;
        o.u[0] = (m0.x || (k0 + 0) > q) ? 0 : 0xFFFFu;
        o.u[1] = (m0.y || (k0 + 1) > q) ? 0 : 0xFFFFu;
        o.u[2] = (m0.z || (k0 + 2) > q) ? 0 : 0xFFFFu;
        o.u[3] = (m0.w || (k0 + 3) > q) ? 0 : 0xFFFFu;
        o.u[4] = (m1.x || (k0 + 4) > q) ? 0 : 0xFFFFu;
        o.u[5] = (m1.y || (k0 + 5) > q) ? 0 : 0xFFFFu;
        o.u[6] = (m1.z || (k0 + 6) > q) ? 0 : 0xFFFFu;
        o.u[7] = (m1.w || (k0 + 7) > q) ? 0 : 0xFFFFu;
        *(uint4*)(EM + i) = o.v;
    }
}

// ---------------------------------------------------------------------------
// conv_w4: W [1024][1024] fp32 -> W^T bf16; z=0..2 -> Wq/Wk/Wv into WcatT,
// z=3 -> Wo into WoT (ws V-slot, free from t=0 now).
// ---------------------------------------------------------------------------
__global__ __launch_bounds__(256)
void conv_w4(const float* __restrict__ Wq, const float* __restrict__ Wk,
             const float* __restrict__ Wv, const float* __restrict__ Wo,
             bf16* __restrict__ WT, bf16* __restrict__ WoT)
{
    const int z = blockIdx.z;
    const float* W = (z == 0) ? Wq : (z == 1) ? Wk : (z == 2) ? Wv : Wo;
    bf16* dst = (z < 3) ? (WT + (size_t)z * kDM * kDM) : WoT;
    __shared__ unsigned short Ls[64][STR];
    const int k0 = blockIdx.x * 64, n0 = blockIdx.y * 64;
    const int tid = threadIdx.x;
    const int r16 = tid >> 4, c4 = (tid & 15) * 4;
    #pragma unroll
    for (int it = 0; it < 4; ++it) {
        const int r = it * 16 + r16;
        const float4 v = *(const float4*)(W + (size_t)(k0 + r) * kDM + n0 + c4);
        Ls[c4 + 0][r] = f2bf(v.x); Ls[c4 + 1][r] = f2bf(v.y);
        Ls[c4 + 2][r] = f2bf(v.z); Ls[c4 + 3][r] = f2bf(v.w);
    }
    __syncthreads();
    #pragma unroll
    for (int it = 0; it < 4; ++it) {
        const int rn = it * 16 + r16;
        ushort4 u;
        u.x = Ls[rn][c4 + 0]; u.y = Ls[rn][c4 + 1];
        u.z = Ls[rn][c4 + 2]; u.w = Ls[rn][c4 + 3];
        *(ushort4*)(dst + (size_t)(n0 + rn) * kDM + k0 + c4) = u;
    }
}

// ---------------------------------------------------------------------------
// qkv_mfma v3: A[8192][1024] @ WcatT[3072][1024]^T (r5 single-buffer loop).
// p==0 -> Q (prescaled 0.125*log2e), p==1 -> K: scatter to ws [B,H,S,64].
// p==2 -> V: transposed epilogue writes VT[bh][64][2048] directly via a
// 16KB XOR-swizzled LDS transpose (vtrans kernel eliminated).
// ---------------------------------------------------------------------------
__global__ __launch_bounds__(256)
void qkv_mfma(const bf16* __restrict__ A, const bf16* __restrict__ BT,
              bf16* __restrict__ ws, bf16* __restrict__ VTp)
{
    __shared__ __align__(16) unsigned short SM[8192];        // 16 KB
    unsigned short (*At)[32] = (unsigned short (*)[32])SM;          // [128][32]
    unsigned short (*Bt)[32] = (unsigned short (*)[32])(SM + 4096); // [128][32]
    const int tid = threadIdx.x;
    const int w = tid >> 6, lane = tid & 63;
    const int quad = (tid >> 4) & 3, col = tid & 15;
    const int wm = w >> 1, wn = w & 1;
    const int flat = blockIdx.x + blockIdx.y * 24;
    const int xcd = flat & 7;
    const int i2 = flat >> 3;                  // [0,192)
    const int n0 = (xcd * 3 + (i2 % 3)) * 128;
    const int m0 = (i2 / 3) * 128;

    const bf16* pA = A  + (size_t)(m0 + w * 32 + (lane >> 2)) * kDM + (lane & 3) * 8;
    const bf16* pB = BT + (size_t)(n0 + w * 32 + (lane >> 2)) * kDM + (lane & 3) * 8;
    unsigned short* lA = &At[w * 32][0];
    unsigned short* lB = &Bt[w * 32][0];

    floatx4 acc[4][4];
    #pragma unroll
    for (int i = 0; i < 4; ++i)
        #pragma unroll
        for (int j = 0; j < 4; ++j) acc[i][j] = (floatx4){0.f, 0.f, 0.f, 0.f};

    for (int k0 = 0; k0 < kDM; k0 += 32) {
        __syncthreads();
        gl_lds16(pA + k0, lA);
        gl_lds16(pA + k0 + 16 * kDM, lA + 16 * 32);
        gl_lds16(pB + k0, lB);
        gl_lds16(pB + k0 + 16 * kDM, lB + 16 * 32);
        __syncthreads();
        short8 aA[4], bB[4];
        #pragma unroll
        for (int i = 0; i < 4; ++i)
            aA[i] = *(const short8*)&At[wm * 64 + i * 16 + col][quad * 8];
        #pragma unroll
        for (int j = 0; j < 4; ++j)
            bB[j] = *(const short8*)&Bt[wn * 64 + j * 16 + col][quad * 8];
        #pragma unroll
        for (int i = 0; i < 4; ++i)
            #pragma unroll
            for (int j = 0; j < 4; ++j)
                acc[i][j] = __builtin_amdgcn_mfma_f32_16x16x32_bf16(aA[i], bB[j], acc[i][j], 0, 0, 0);
    }

    const int p  = n0 >> 10;
    const int nn = n0 & 1023;

    if (p == 2) {
        // ---- V panel: transposed write to VT[bh][64 d][2048 s] ----
        // wn selects the head within this 128-n panel; d = j*16+col, s = m&2047.
        const int bb  = m0 >> 11;
        const int s0b = m0 & 2047;
        const int hA  = nn >> 6;
        #pragma unroll
        for (int hh = 0; hh < 2; ++hh) {
            __syncthreads();
            if (wn == hh) {                      // waves hh and hh+2 own this head
                #pragma unroll
                for (int i = 0; i < 4; ++i) {
                    const int s = wm * 64 + i * 16 + quad * 4;
                    #pragma unroll
                    for (int jj = 0; jj < 4; ++jj) {
                        const int d = jj * 16 + col;
                        uint2 pk;
                        pk.x = cvt_pk_bf16(acc[i][jj][0], acc[i][jj][1]);
                        pk.y = cvt_pk_bf16(acc[i][jj][2], acc[i][jj][3]);
                        const int sx = s ^ ((d & 7) << 3);   // bank swizzle
                        *(uint2*)&SM[d * 128 + sx] = pk;
                    }
                }
            }
            __syncthreads();
            bf16* dst = VTp + (size_t)(bb * kH + hA + hh) * kDH * kS;
            #pragma unroll
            for (int k = 0; k < 8; ++k) {
                const int d = k * 8 + (tid >> 5);
                const int s = (tid & 31) * 4;
                const int sx = s ^ ((d & 7) << 3);
                *(uint2*)(dst + (size_t)d * kS + s0b + s) = *(const uint2*)&SM[d * 128 + sx];
            }
        }
        return;
    }

    const float scl = (p == 0) ? 0.18033688f : 1.0f;   // 0.125 * log2(e)
    bf16* Out = ws + (size_t)p * kHeadElems;
    #pragma unroll
    for (int i = 0; i < 4; ++i) {
        #pragma unroll
        for (int r = 0; r < 4; ++r) {
            const int m = m0 + wm * 64 + i * 16 + quad * 4 + r;
            const int b = m >> 11, s = m & 2047;
            #pragma unroll
            for (int j = 0; j < 4; ++j) {
                const int n = nn + wn * 64 + j * 16 + col;
                const int h = n >> 6, d = n & 63;
                Out[((size_t)(b * kH + h) * kS + s) * kDH + d] = __float2bfloat16(acc[i][j][r] * scl);
            }
        }
    }
}

// ---------------------------------------------------------------------------
// attn_mfma v7 (round-5, best measured): balanced qtile map + 2-buffer depth-1
// pipeline, 3 blocks/CU. grid (16 qtiles, 64 bh), block 256 = 4 waves x 32 q.
// ---------------------------------------------------------------------------
__global__ __launch_bounds__(256, 3)
void attn_mfma(const bf16* __restrict__ ws, const bf16* __restrict__ VT,
               const unsigned short* __restrict__ EM,
               bf16* __restrict__ Aout)
{
    // XCD-grouped remap: xcd = flat%8 owns bh in [xcd*8, xcd*8+8) -> K+V 4MB = one L2.
    // qtile(k=j>>2, r=j&3) = 4*(3-k) + ((3-k+r)&3): per-CU qtile sums == 30
    // (balanced 68 tiles/CU), bijective, heavy tiles dispatched first.
    const int flat = blockIdx.x + blockIdx.y * 16;
    const int xcd = flat & 7;
    const int idx = flat >> 3;                 // [0,128)
    const int bh  = xcd * 8 + (idx & 7);
    const int j   = idx >> 3;                  // [0,16)
    const int kk  = 3 - (j >> 2);
    const int qtile = 4 * kk + ((kk + (j & 3)) & 3);
    const int q0 = qtile * 128;

    const int b = bh >> 4, h = bh & 15;
    const int tid  = threadIdx.x;
    const int w    = tid >> 6;
    const int lane = tid & 63;
    const int quad = (tid >> 4) & 3;
    const int col  = tid & 15;

    const size_t ho = (size_t)bh * kS * kDH;
    const bf16* Qg  = ws + ho;                 // pre-scaled by 0.125*log2e
    const bf16* Kg  = ws + kHeadElems + ho;
    const bf16* VTg = VT + ho;                 // [64 d][2048 s]

    __shared__ __align__(16) unsigned short Ks[2][64][64];   // XOR-swizzled chunks
    __shared__ __align__(16) unsigned short Vs[2][64][64];
    __shared__ __align__(16) unsigned short Pw[4][2][16][STR];

    const int qw = q0 + w * 32;
    const int swz = col & 7;                    // read-side XOR swizzle
    const int sch = (lane & 7) ^ (lane >> 3);   // staging source-chunk swizzle

    // Q B-fragments for both 16-row subtiles (n=q=col, k=d)
    short8 bQ[2][2];
    const unsigned short* EMq[2];
    #pragma unroll
    for (int sub = 0; sub < 2; ++sub) {
        const bf16* qrow = Qg + (size_t)(qw + sub * 16 + col) * kDH;
        bQ[sub][0] = *(const short8*)(qrow + quad * 8);
        bQ[sub][1] = *(const short8*)(qrow + 32 + quad * 8);
        EMq[sub] = EM + (size_t)(qw + sub * 16 + col) * kS;
    }

    floatx4 Ov[2][4];
    #pragma unroll
    for (int sub = 0; sub < 2; ++sub)
        #pragma unroll
        for (int dg = 0; dg < 4; ++dg) Ov[sub][dg] = (floatx4){0.f, 0.f, 0.f, 0.f};
    float lacc[2] = {0.f, 0.f};

    const int nt = qtile * 2 + 2;               // block-uniform tile count

    // cooperative stage of tile kt into buffer buf (4 gl_lds per wave)
    auto STAGE = [&](int buf, int kt) {
        const bf16* Kt = Kg  + (size_t)(kt * 64) * kDH;
        const bf16* Vt = VTg + kt * 64;
        #pragma unroll
        for (int t = 0; t < 2; ++t) {
            const int rbase = (t * 4 + w) * 8;
            const int r = rbase + (lane >> 3);
            gl_lds16(Kt + (size_t)r * kDH + sch * 8, &Ks[buf][rbase][0]);
            gl_lds16(Vt + (size_t)r * kS  + sch * 8, &Vs[buf][rbase][0]);
        }
    };

    STAGE(0, 0);
    asm volatile("s_waitcnt vmcnt(0)" ::: "memory");
    __builtin_amdgcn_s_barrier();
    __builtin_amdgcn_sched_barrier(0);

    int cur = 0;
    for (int kt = 0; kt < nt; ++kt) {
        const int kt64 = kt * 64;
        const bool doC = (kt64 <= qw + 31);     // wave-uniform compute guard

        // EM loads for THIS tile, issued BEFORE the new staging loads.
        uint2 em[2][4];
        if (doC) {
            #pragma unroll
            for (int sub = 0; sub < 2; ++sub)
                #pragma unroll
                for (int g = 0; g < 4; ++g)
                    em[sub][g] = *(const uint2*)(EMq[sub] + kt64 + g * 16 + quad * 4);
            __builtin_amdgcn_sched_barrier(0);  // pin EM-issue before STAGE
        }

        if (kt + 1 < nt) STAGE(cur ^ 1, kt + 1);   // depth-1 prefetch

        if (doC) {
            // ---- S^T = K Q^T : A=K rows (LDS), B=Q regs; C: row=key, col=q ----
            floatx4 sg[2][4];
            __builtin_amdgcn_s_setprio(1);
            #pragma unroll
            for (int g = 0; g < 4; ++g) {
                const int krow = g * 16 + col;
                const short8 aK0 = *(const short8*)&Ks[cur][krow][(quad ^ swz) * 8];
                const short8 aK1 = *(const short8*)&Ks[cur][krow][((4 + quad) ^ swz) * 8];
                floatx4 sA = {0.f, 0.f, 0.f, 0.f}, sB = {0.f, 0.f, 0.f, 0.f};
                sA = __builtin_amdgcn_mfma_f32_16x16x32_bf16(aK0, bQ[0][0], sA, 0, 0, 0);
                sA = __builtin_amdgcn_mfma_f32_16x16x32_bf16(aK1, bQ[0][1], sA, 0, 0, 0);
                sB = __builtin_amdgcn_mfma_f32_16x16x32_bf16(aK0, bQ[1][0], sB, 0, 0, 0);
                sB = __builtin_amdgcn_mfma_f32_16x16x32_bf16(aK1, bQ[1][1], sB, 0, 0, 0);
                sg[0][g] = sA; sg[1][g] = sB;
            }
            __builtin_amdgcn_s_setprio(0);

            // ---- softmax numerator (exp2), cvt_pk pack, AND expanded mask ----
            #pragma unroll
            for (int sub = 0; sub < 2; ++sub) {
                const int qbase = qw + sub * 16;
                const bool needC = (kt64 + 63 > qbase);
                float lc = 0.f;
                #pragma unroll
                for (int g = 0; g < 4; ++g) {
                    const float p0 = EXP2(sg[sub][g][0]);
                    const float p1 = EXP2(sg[sub][g][1]);
                    const float p2 = EXP2(sg[sub][g][2]);
                    const float p3 = EXP2(sg[sub][g][3]);
                    if (needC) {
                        const int kb = kt64 + g * 16 + quad * 4;
                        const int qme = qbase + col;
                        lc += (kb + 0 <= qme) ? p0 : 0.f;
                        lc += (kb + 1 <= qme) ? p1 : 0.f;
                        lc += (kb + 2 <= qme) ? p2 : 0.f;
                        lc += (kb + 3 <= qme) ? p3 : 0.f;
                    } else {
                        lc += (p0 + p1) + (p2 + p3);
                    }
                    uint2 pk;
                    pk.x = cvt_pk_bf16(p0, p1) & em[sub][g].x;
                    pk.y = cvt_pk_bf16(p2, p3) & em[sub][g].y;
                    *(uint2*)&Pw[w][sub][col][g * 16 + quad * 4] = pk;
                }
                lacc[sub] += lc;
            }

            // ---- O += P V : A=P (wave-private LDS), B=V^T rows (LDS) ----
            const short8 aP[2][2] = {
                { *(const short8*)&Pw[w][0][col][quad * 8],
                  *(const short8*)&Pw[w][0][col][32 + quad * 8] },
                { *(const short8*)&Pw[w][1][col][quad * 8],
                  *(const short8*)&Pw[w][1][col][32 + quad * 8] } };
            __builtin_amdgcn_s_setprio(1);
            #pragma unroll
            for (int dg = 0; dg < 4; ++dg) {
                const int vrow = dg * 16 + col;
                const short8 bV0 = *(const short8*)&Vs[cur][vrow][(quad ^ swz) * 8];
                const short8 bV1 = *(const short8*)&Vs[cur][vrow][((4 + quad) ^ swz) * 8];
                Ov[0][dg] = __builtin_amdgcn_mfma_f32_16x16x32_bf16(aP[0][0], bV0, Ov[0][dg], 0, 0, 0);
                Ov[0][dg] = __builtin_amdgcn_mfma_f32_16x16x32_bf16(aP[0][1], bV1, Ov[0][dg], 0, 0, 0);
                Ov[1][dg] = __builtin_amdgcn_mfma_f32_16x16x32_bf16(aP[1][0], bV0, Ov[1][dg], 0, 0, 0);
                Ov[1][dg] = __builtin_amdgcn_mfma_f32_16x16x32_bf16(aP[1][1], bV1, Ov[1][dg], 0, 0, 0);
            }
            __builtin_amdgcn_s_setprio(0);
        }

        asm volatile("s_waitcnt vmcnt(0)" ::: "memory");   // staged tile landed
        __builtin_amdgcn_s_barrier();
        __builtin_amdgcn_sched_barrier(0);
        cur ^= 1;
    }

    // ---- normalize and write ----
    #pragma unroll
    for (int sub = 0; sub < 2; ++sub) {
        float l = lacc[sub];
        l += __shfl_xor(l, 16, 64);
        l += __shfl_xor(l, 32, 64);
        const float linv = 1.f / l;
        #pragma unroll
        for (int r = 0; r < 4; ++r) {
            const float sc = __shfl(linv, quad * 4 + r, 64);
            const int q = qw + sub * 16 + quad * 4 + r;
            bf16* orow = Aout + ((size_t)(b * kS + q)) * kDM + h * kDH;
            #pragma unroll
            for (int dg = 0; dg < 4; ++dg)
                orow[dg * 16 + col] = __float2bfloat16(Ov[sub][dg][r] * sc);
        }
    }
}

// ---------------------------------------------------------------------------
// out_mfma (round-5 single-buffer): Aout bf16 @ WoT^T -> fp32 d_out.
// XCD-local: n-panel per XCD.
// ---------------------------------------------------------------------------
__global__ __launch_bounds__(256)
void out_mfma(const bf16* __restrict__ A, const bf16* __restrict__ BT,
              float* __restrict__ Out)
{
    __shared__ __align__(16) unsigned short At[128][32];
    __shared__ __align__(16) unsigned short Bt[128][32];
    const int tid = threadIdx.x;
    const int w = tid >> 6, lane = tid & 63;
    const int quad = (tid >> 4) & 3, col = tid & 15;
    const int wm = w >> 1, wn = w & 1;
    const int flat = blockIdx.x + blockIdx.y * 8;
    const int n0 = (flat & 7) * 128;
    const int m0 = (flat >> 3) * 128;

    const bf16* pA = A  + (size_t)(m0 + w * 32 + (lane >> 2)) * kDM + (lane & 3) * 8;
    const bf16* pB = BT + (size_t)(n0 + w * 32 + (lane >> 2)) * kDM + (lane & 3) * 8;
    unsigned short* lA = &At[w * 32][0];
    unsigned short* lB = &Bt[w * 32][0];

    floatx4 acc[4][4];
    #pragma unroll
    for (int i = 0; i < 4; ++i)
        #pragma unroll
        for (int j = 0; j < 4; ++j) acc[i][j] = (floatx4){0.f, 0.f, 0.f, 0.f};

    for (int k0 = 0; k0 < kDM; k0 += 32) {
        __syncthreads();
        gl_lds16(pA + k0, lA);
        gl_lds16(pA + k0 + 16 * kDM, lA + 16 * 32);
        gl_lds16(pB + k0, lB);
        gl_lds16(pB + k0 + 16 * kDM, lB + 16 * 32);
        __syncthreads();
        short8 aA[4], bB[4];
        #pragma unroll
        for (int i = 0; i < 4; ++i)
            aA[i] = *(const short8*)&At[wm * 64 + i * 16 + col][quad * 8];
        #pragma unroll
        for (int j = 0; j < 4; ++j)
            bB[j] = *(const short8*)&Bt[wn * 64 + j * 16 + col][quad * 8];
        #pragma unroll
        for (int i = 0; i < 4; ++i)
            #pragma unroll
            for (int j = 0; j < 4; ++j)
                acc[i][j] = __builtin_amdgcn_mfma_f32_16x16x32_bf16(aA[i], bB[j], acc[i][j], 0, 0, 0);
    }

    #pragma unroll
    for (int i = 0; i < 4; ++i)
        #pragma unroll
        for (int r = 0; r < 4; ++r) {
            const int m = m0 + wm * 64 + i * 16 + quad * 4 + r;
            #pragma unroll
            for (int j = 0; j < 4; ++j)
                Out[(size_t)m * kDM + n0 + wn * 64 + j * 16 + col] = acc[i][j][r];
        }
}

// ---------------------------------------------------------------------------
extern "C" void kernel_launch(void* const* d_in, const int* in_sizes, int n_in,
                              void* d_out, int out_size, void* d_ws, size_t ws_size,
                              hipStream_t stream)
{
    const float* Xq       = (const float*)d_in[0];
    // d_in[1] = mask_bef (causal, analytic — unused)
    const int*   mask_aft = (const int*)d_in[2];
    const float* Wq       = (const float*)d_in[3];
    const float* Wk       = (const float*)d_in[4];
    const float* Wv       = (const float*)d_in[5];
    const float* Wo       = (const float*)d_in[6];
    float* out = (float*)d_out;

    bf16* ws   = (bf16*)d_ws;
    bf16* Xbf  = ws + 3 * kHeadElems;      // aliased: Xbf (qkv input) -> Aout (attn output)
    bf16* Aout = Xbf;
    bf16* WoT  = ws + 2 * kHeadElems;      // former V slot — free from t=0 now

    bf16* WcatT = (bf16*)d_out + 262144;                                   // +512KB, 6MB
    bf16* VT    = (bf16*)((char*)d_out + 8u * 1024 * 1024);                // +8MB, 16MB
    unsigned short* EMp = (unsigned short*)((char*)d_out + 24u * 1024 * 1024); // +24MB, 8MB

    fused_pre<<<dim3(6144), 256, 0, stream>>>(Xq, Xbf, mask_aft, EMp);
    conv_w4 <<<dim3(16, 16, 4), 256, 0, stream>>>(Wq, Wk, Wv, Wo, WcatT, WoT);
    qkv_mfma<<<dim3(24, 64), 256, 0, stream>>>(Xbf, WcatT, ws, VT);
    attn_mfma<<<dim3(16, 64), 256, 0, stream>>>(ws, VT, EMp, Aout);
    out_mfma<<<dim3(8, 64), 256, 0, stream>>>(Aout, WoT, out);
}